// Round 15
// baseline (121.221 us; speedup 1.0000x reference)
//
#include <hip/hip_runtime.h>
#include <math.h>

typedef __bf16 bf16x8 __attribute__((ext_vector_type(8)));
typedef __bf16 bf16x2 __attribute__((ext_vector_type(2)));
typedef float f32x4 __attribute__((ext_vector_type(4)));
typedef float f32x16 __attribute__((ext_vector_type(16)));
typedef unsigned int u32x2 __attribute__((ext_vector_type(2)));

static constexpr int TSEQ = 4096;
static constexpr int CDIM = 768;
static constexpr int NHEAD = 12;
static constexpr int HDIM = 64;
static constexpr int QKVW = 2304;

__device__ inline unsigned short f32_to_bf16(float f) {
    unsigned int u = __builtin_bit_cast(unsigned int, f);
    u = (u + 0x7FFFu + ((u >> 16) & 1u)) >> 16;
    return (unsigned short)u;
}

__device__ inline f32x4 mfma16(bf16x8 a, bf16x8 b, f32x4 c) {
    return __builtin_amdgcn_mfma_f32_16x16x32_bf16(a, b, c, 0, 0, 0);
}

__device__ inline f32x16 mfma32(bf16x8 a, bf16x8 b, f32x16 c) {
    return __builtin_amdgcn_mfma_f32_32x32x16_bf16(a, b, c, 0, 0, 0);
}

// v_permlane32_swap_b32 via builtin (guaranteed two-result semantics):
// new_a[32:63] = old_b[0:31], new_b[0:31] = old_a[32:63].
__device__ inline void pls32(unsigned int &a, unsigned int &b) {
    u32x2 r = __builtin_amdgcn_permlane32_swap(a, b, false, false);
    a = r[0];
    b = r[1];
}

__device__ inline float swap_fmax(float x) {
    unsigned int a = __builtin_bit_cast(unsigned int, x), b = a;
    pls32(a, b);
    return fmaxf(__builtin_bit_cast(float, a), __builtin_bit_cast(float, b));
}

__device__ inline float swap_fadd(float x) {
    unsigned int a = __builtin_bit_cast(unsigned int, x), b = a;
    pls32(a, b);
    return __builtin_bit_cast(float, a) + __builtin_bit_cast(float, b);
}

__device__ inline unsigned int pkbf(float a, float b) {
    bf16x2 t;
    t[0] = (__bf16)a;
    t[1] = (__bf16)b;
    return __builtin_bit_cast(unsigned int, t);
}

#define GLOAD_LDS16(g, s)                                                        \
    __builtin_amdgcn_global_load_lds(                                            \
        (const __attribute__((address_space(1))) void*)(g),                      \
        (__attribute__((address_space(3))) void*)(s), 16, 0, 0)

// ---------------------------------------------------------------------------
// fused fp32 -> bf16 convert for x, W_qkv, W_out (one launch)
// ---------------------------------------------------------------------------
__global__ __launch_bounds__(256) void cvt3_f32_bf16(
    const float* __restrict__ a, int na, unsigned short* __restrict__ oa,
    const float* __restrict__ b, int nb, unsigned short* __restrict__ ob,
    const float* __restrict__ c, int nc, unsigned short* __restrict__ oc)
{
    int i = (blockIdx.x * 256 + threadIdx.x) * 4;
    const float* src;
    unsigned short* dst;
    if (i < na) {
        src = a + i; dst = oa + i;
    } else if ((i - na) < nb) {
        src = b + (i - na); dst = ob + (i - na);
    } else if ((i - na - nb) < nc) {
        src = c + (i - na - nb); dst = oc + (i - na - nb);
    } else {
        return;
    }
    float4 v = *reinterpret_cast<const float4*>(src);
    ushort4 o;
    o.x = f32_to_bf16(v.x); o.y = f32_to_bf16(v.y);
    o.z = f32_to_bf16(v.z); o.w = f32_to_bf16(v.w);
    *reinterpret_cast<ushort4*>(dst) = o;
}

// ---------------------------------------------------------------------------
// NT GEMM bf16 MFMA, tile T x T (T in {64,128}), BK=32, 4 waves (2x2),
// single-barrier double-buffered staging (verified round-13 schedule):
// per K-step { __syncthreads (drains stage(k) for all waves); issue
// stage(k+1) into other buffer (flight hidden under compute(k));
// compute(k) }.
// Round-15: BOTH gemms at T=64. gemm1's T=128 grid was 576 blocks =
// 2.25/CU (structural ~30% tail: 64 CUs run a 3rd block while 192 idle);
// T=64 -> 2304 blocks = 9/CU, LDS 16KB, ~8 resident blocks/CU.
// A/B panels are L2/L3-resident so the 2x tile-traffic stays off HBM.
// VT=1: blocks with n0 >= 1536 (V columns of the QKV GEMM) write their
// output TRANSPOSED to vt via an LDS bounce Ts[T][T+8] aliasing the
// staging buffers (barrier before reuse) -- generalized to T=64.
// ---------------------------------------------------------------------------
template <int OUT_BF16, int VT, int T>
__global__ __launch_bounds__(256) void gemm_nt_mfma(
    const unsigned short* __restrict__ A, const unsigned short* __restrict__ B,
    void* __restrict__ Cv, int M, int N, int K, int scale_cols, float scale,
    unsigned short* __restrict__ vt)
{
    // As dbuf [2][T][32] at 0, Bs dbuf [2][T][32] at 2*T*32 (elements).
    // VT epilogue reuses smem as Ts[T][T+8].
    constexpr int TB = T * 32;                  // one buffer, elements
    constexpr int TSZ = T * (T + 8);            // VT bounce, elements
    constexpr int SMEM = (VT && TSZ > 4 * TB) ? TSZ : 4 * TB;
    __shared__ unsigned short smem[SMEM];

    constexpr int NF = T / 32;                  // 16-wide frags per wave dim
    constexpr int NP = T / 64;                  // stage issues per matrix

    const int tid = threadIdx.x;
    const int w = tid >> 6, l = tid & 63;
    const int l16 = l & 15, lg = l >> 4;
    const int wy = w >> 1, wx = w & 1;
    const int m0 = blockIdx.y * T, n0 = blockIdx.x * T;
    const float cs = (n0 < scale_cols) ? scale : 1.0f;

    f32x4 acc[NF][NF];
#pragma unroll
    for (int i = 0; i < NF; ++i)
#pragma unroll
        for (int j = 0; j < NF; ++j) {
            f32x4 z = {0.f, 0.f, 0.f, 0.f};
            acc[i][j] = z;
        }

    const int lrow = l >> 2;
    const int lkb = (l & 3) * 8;

    // stage K-step k0 into buffer buf (A: Tx32, B: Tx32; 16B/lane x NP x2)
    auto stage = [&](int k0, int buf) {
#pragma unroll
        for (int p = 0; p < NP; ++p) {
            int c = w * NP + p;
            const unsigned short* ga = &A[(size_t)(m0 + c * 16 + lrow) * K + k0 + lkb];
            GLOAD_LDS16(ga, &smem[buf * TB + c * 16 * 32]);
            const unsigned short* gb = &B[(size_t)(n0 + c * 16 + lrow) * K + k0 + lkb];
            GLOAD_LDS16(gb, &smem[2 * TB + buf * TB + c * 16 * 32]);
        }
    };

    const int nk = K >> 5;
    stage(0, 0);

    for (int kk = 0; kk < nk; ++kk) {
        // drains stage(kk) (issued last iter / prologue) for all waves;
        // also fences compute(kk-1)'s ds_reads -> stage(kk+1) overwrite of
        // buffer (kk+1)&1 (last read at compute(kk-1)) is safe.
        __syncthreads();
        if (kk + 1 < nk) stage((kk + 1) * 32, (kk + 1) & 1);

        const unsigned short* as = &smem[(kk & 1) * TB];
        const unsigned short* bs = &smem[2 * TB + (kk & 1) * TB];
        bf16x8 af[NF], bf[NF];
#pragma unroll
        for (int i = 0; i < NF; ++i) {
            af[i] = *reinterpret_cast<const bf16x8*>(
                &as[(wy * (T / 2) + i * 16 + l16) * 32 + lg * 8]);
            bf[i] = *reinterpret_cast<const bf16x8*>(
                &bs[(wx * (T / 2) + i * 16 + l16) * 32 + lg * 8]);
        }
        __builtin_amdgcn_s_setprio(1);
#pragma unroll
        for (int i = 0; i < NF; ++i)
#pragma unroll
            for (int j = 0; j < NF; ++j)
                acc[i][j] = mfma16(af[i], bf[j], acc[i][j]);
        __builtin_amdgcn_s_setprio(0);
    }

    if (VT && n0 >= 1536) {
        // transposed epilogue: acc -> Ts[cc][rr] (chan-major, stride T+8),
        // then coalesced row stores to vt[(chan)*TSEQ + time]. Ts aliases
        // the staging buffers -> barrier before reuse.
        __syncthreads();
        unsigned short* Ts = &smem[0];
#pragma unroll
        for (int i = 0; i < NF; ++i)
#pragma unroll
            for (int j = 0; j < NF; ++j)
#pragma unroll
                for (int r = 0; r < 4; ++r) {
                    int rr = wy * (T / 2) + i * 16 + lg * 4 + r;
                    int cc = wx * (T / 2) + j * 16 + l16;
                    Ts[cc * (T + 8) + rr] = f32_to_bf16(acc[i][j][r]);
                }
        __syncthreads();
        constexpr int CH = T / 8;               // 16B chunks per row
#pragma unroll
        for (int p = 0; p < T * CH / 256; ++p) {
            int idx = p * 256 + tid;
            int row = idx / CH;                 // chan-rel 0..T-1
            int ch = idx % CH;                  // 16B chunk
            uint4 v = *reinterpret_cast<const uint4*>(
                &Ts[row * (T + 8) + ch * 8]);
            *reinterpret_cast<uint4*>(
                &vt[(size_t)(n0 - 1536 + row) * TSEQ + m0 + ch * 8]) = v;
        }
        return;
    }

#pragma unroll
    for (int i = 0; i < NF; ++i)
#pragma unroll
        for (int j = 0; j < NF; ++j)
#pragma unroll
            for (int r = 0; r < 4; ++r) {
                int row = m0 + wy * (T / 2) + i * 16 + lg * 4 + r;
                int col = n0 + wx * (T / 2) + j * 16 + l16;
                float v = acc[i][j][r] * cs;
                if (OUT_BF16)
                    ((unsigned short*)Cv)[(size_t)row * N + col] = f32_to_bf16(v);
                else
                    ((float*)Cv)[(size_t)row * N + col] = v;
            }
}

// ---------------------------------------------------------------------------
// Causal flash attention, 32x32x16 MFMA, swapped operands end-to-end:
//   S^T = mfma32(K, Q)  -> lane holds col q = l&31, rows = kv  (q lane-local)
//   O^T = mfma32(V^T, P)-> lane holds col q = l&31, rows = d   (q lane-local)
// Byte-identical to the verified round-10 optimum (73.9 us). Schedule
// (per KV tile, 2 barriers):
//   A: K(it) landed; PV(it-1) V-reads done  -> stageV(it) (hidden under
//      QK+softmax)  -> QK -> mask -> softmax
//   B: V(it) landed; QK K-reads done        -> stageK(it+1) (hidden under
//      pack+PV)     -> pack P -> PV
// Both K and V single-buffered; LDS read/stage addresses loop-invariant.
// Softmax: in-register max3 trees + one permlane32_swap; P->bf16 via cvt_pk
// pairs + permlane32_swap (T12); defer-max (T13, THR=8); exp2-domain
// (Q pre-scaled by 0.125*log2e in the QKV GEMM). T5 setprio on MFMA.
// 4 waves = 2 q-subtiles x 2 kv-halves, merged via LDS at the end.
// ---------------------------------------------------------------------------
__global__ __launch_bounds__(256, 3) void attn_mfma(
    const unsigned short* __restrict__ qkv,   // [4096][2304] bf16
    const unsigned short* __restrict__ vtg,   // [768][4096] bf16
    unsigned short* __restrict__ att)         // [4096][768] bf16
{
    __shared__ unsigned short Ks[2][64 * 64];   // [kv-half] single 16 KiB
    __shared__ unsigned short Vs[2][64 * 64];   // [kv-half] single 16 KiB
    __shared__ float Ms[2][64], Ls[2][64];

    const int b = blockIdx.x;
    const int h = b % NHEAD;
    const int qt = (TSEQ / 64 - 1) - b / NHEAD;   // LPT: heaviest first
    const int q0 = qt * 64;
    const int tid = threadIdx.x;
    const int w = tid >> 6, l = tid & 63;
    const int qs = w >> 1;        // q sub-block (32 rows)
    const int wk = w & 1;         // kv half
    const int l32 = l & 31, hh = l >> 5;

    const int NT = qt + 1;
    const int NH = NT >> 1;           // tiles in first half
    const int ITER = NT - NH;         // loop count (= second-half tiles)
    const int tbase = wk ? NH : 0;
    const int tcnt  = wk ? ITER : NH;

    // Q B-fragments: Q[q0+qs*32+l32][ks*16 + hh*8 .. +7], pre-scaled
    bf16x8 qf[4];
    {
        const unsigned short* qrow =
            &qkv[(size_t)(q0 + qs * 32 + l32) * QKVW + h * HDIM + hh * 8];
#pragma unroll
        for (int ks = 0; ks < 4; ++ks)
            qf[ks] = *reinterpret_cast<const bf16x8*>(qrow + ks * 16);
    }

    f32x16 oacc0, oacc1;
#pragma unroll
    for (int i = 0; i < 16; ++i) { oacc0[i] = 0.f; oacc1[i] = 0.f; }
    float m_s = -1e30f, l_s = 0.f;

    // loop-invariant zero accumulator (C operand of first QK mfma)
    f32x16 zf;
#pragma unroll
    for (int i = 0; i < 16; ++i) zf[i] = 0.f;

    // loop-invariant swizzled LDS read bases (element units)
    const int cx = l32 & 7;
    const unsigned short* kb8[4];
    const unsigned short* vb8[4];
#pragma unroll
    for (int ks = 0; ks < 4; ++ks) {
        const int sw = l32 * 64 + (((2 * ks + hh) ^ cx) * 8);
        kb8[ks] = &Ks[wk][sw];
        vb8[ks] = &Vs[wk][sw];
    }

    // stage K tile kt (64 kv-rows x 64 d, XOR-swizzled via pre-swizzled
    // global source, LDS linear) into Ks[wk]; 2 waves x 4 issues each.
    auto stageK = [&](int kt) {
#pragma unroll
        for (int i = 0; i < 4; ++i) {
            int u = i * 128 + qs * 64 + l;       // 16B unit in 8KB tile
            int r = u >> 3;
            int sc = (u & 7) ^ (r & 7);
            const unsigned short* g =
                &qkv[(size_t)(kt * 64 + r) * QKVW + CDIM + h * HDIM + sc * 8];
            GLOAD_LDS16(g, &Ks[wk][(i * 128 + qs * 64) * 8]);
        }
    };

    // stage V^T tile kt (64 d-rows x 64 kv, same swizzle; kv-contiguous
    // rows -> coalesced) into Vs[wk].
    auto stageV = [&](int kt) {
#pragma unroll
        for (int i = 0; i < 4; ++i) {
            int u = i * 128 + qs * 64 + l;       // 16B unit in 8KB tile
            int r = u >> 3;                      // d-row 0..63
            int sc = (u & 7) ^ (r & 7);          // swizzled kv-chunk
            const unsigned short* g =
                &vtg[(size_t)(h * HDIM + r) * TSEQ + kt * 64 + sc * 8];
            GLOAD_LDS16(g, &Vs[wk][(i * 128 + qs * 64) * 8]);
        }
    };

    if (tcnt > 0) stageK(tbase);

    for (int it = 0; it < ITER; ++it) {
        const bool act = it < tcnt;
        const int kt = tbase + it;

        // Barrier A: K(it) (staged after B(it-1) / prologue) landed for all
        // waves; PV(it-1) reads of Vs done -> V overwrite safe.
        __syncthreads();

        if (act) stageV(kt);     // lands during QK+softmax, checked at B

        f32x16 s0, s1;
        if (act) {
            // QK: S^T[kv][q], A = K rows from LDS, B = Q rows in regs
            __builtin_amdgcn_s_setprio(1);
            {
                bf16x8 k0 = *reinterpret_cast<const bf16x8*>(kb8[0]);
                bf16x8 k1 = *reinterpret_cast<const bf16x8*>(kb8[0] + 2048);
                s0 = mfma32(k0, qf[0], zf);
                s1 = mfma32(k1, qf[0], zf);
            }
#pragma unroll
            for (int ks = 1; ks < 4; ++ks) {
                bf16x8 k0 = *reinterpret_cast<const bf16x8*>(kb8[ks]);
                bf16x8 k1 = *reinterpret_cast<const bf16x8*>(kb8[ks] + 2048);
                s0 = mfma32(k0, qf[ks], s0);
                s1 = mfma32(k1, qf[ks], s1);
            }
            __builtin_amdgcn_s_setprio(0);

            // causal mask (diag tile only; always in second half)
            if (kt == qt) {
                const int qq = qs * 32 + l32;
#pragma unroll
                for (int rr = 0; rr < 16; ++rr) {
                    int kv0 = (rr & 3) + 8 * (rr >> 2) + 4 * hh;
                    if (kv0 > qq) s0[rr] = -1e30f;
                    if (kv0 + 32 > qq) s1[rr] = -1e30f;
                }
            }

            // ---- online softmax, q lane-local (v_max3 tree) ----
            float ma = fmaxf(fmaxf(s0[0], s0[1]), s0[2]);
            float mb = fmaxf(fmaxf(s0[3], s0[4]), s0[5]);
            float mc = fmaxf(fmaxf(s0[6], s0[7]), s0[8]);
            float md = fmaxf(fmaxf(s0[9], s0[10]), s0[11]);
            float me = fmaxf(fmaxf(s0[12], s0[13]), s0[14]);
            float mf = fmaxf(fmaxf(s0[15], s1[0]), s1[1]);
            float mg = fmaxf(fmaxf(s1[2], s1[3]), s1[4]);
            float mh = fmaxf(fmaxf(s1[5], s1[6]), s1[7]);
            float mi = fmaxf(fmaxf(s1[8], s1[9]), s1[10]);
            float mj = fmaxf(fmaxf(s1[11], s1[12]), s1[13]);
            float mk = fmaxf(s1[14], s1[15]);
            ma = fmaxf(fmaxf(ma, mb), mc);
            md = fmaxf(fmaxf(md, me), mf);
            mg = fmaxf(fmaxf(mg, mh), mi);
            mj = fmaxf(mj, mk);
            float mx = fmaxf(fmaxf(ma, md), fmaxf(mg, mj));
            mx = swap_fmax(mx);

            if (!__all(mx <= m_s + 8.0f)) {        // T13 defer-max
                float mnew = fmaxf(m_s, mx);
                float alpha = exp2f(m_s - mnew);
                m_s = mnew;
                l_s *= alpha;
#pragma unroll
                for (int i = 0; i < 16; ++i) {
                    oacc0[i] *= alpha;
                    oacc1[i] *= alpha;
                }
            }

#pragma unroll
            for (int i = 0; i < 16; ++i) {
                s0[i] = exp2f(s0[i] - m_s);
                s1[i] = exp2f(s1[i] - m_s);
            }
            float ts = 0.f;
#pragma unroll
            for (int i = 0; i < 16; ++i) ts += s0[i] + s1[i];
            l_s += swap_fadd(ts);
        }

        // Barrier B: V(it) landed + visible; all QK reads of Ks done, so
        // stageK(it+1) below may overwrite the single K buffer. Its flight
        // is hidden under pack+PV and drained by the next barrier A.
        __syncthreads();

        if (it + 1 < tcnt) stageK(tbase + it + 1);

        if (act) {
            // ---- pack P to PV B-fragments (T12: cvt_pk + permlane32_swap)
            // k-group ks (16 kv): lane needs P[q=l32][kv = ks*16 + hh*8 + j]
            bf16x8 pb[4];
#pragma unroll
            for (int ks = 0; ks < 4; ++ks) {
                const int r0 = (ks & 1) * 8;
                unsigned int w0, w1, w2, w3;
                if (ks < 2) {
                    w0 = pkbf(s0[r0 + 0], s0[r0 + 1]);
                    w1 = pkbf(s0[r0 + 2], s0[r0 + 3]);
                    w2 = pkbf(s0[r0 + 4], s0[r0 + 5]);
                    w3 = pkbf(s0[r0 + 6], s0[r0 + 7]);
                } else {
                    w0 = pkbf(s1[r0 + 0], s1[r0 + 1]);
                    w1 = pkbf(s1[r0 + 2], s1[r0 + 3]);
                    w2 = pkbf(s1[r0 + 4], s1[r0 + 5]);
                    w3 = pkbf(s1[r0 + 6], s1[r0 + 7]);
                }
                pls32(w0, w2);
                pls32(w1, w3);
                uint4 uv = make_uint4(w0, w1, w2, w3);
                pb[ks] = __builtin_bit_cast(bf16x8, uv);
            }

            // ---- O^T += V^T P : V fragments from LDS (invariant addrs)
            __builtin_amdgcn_s_setprio(1);
#pragma unroll
            for (int ks = 0; ks < 4; ++ks) {
                bf16x8 v0 = *reinterpret_cast<const bf16x8*>(vb8[ks]);
                bf16x8 v1 = *reinterpret_cast<const bf16x8*>(vb8[ks] + 2048);
                oacc0 = mfma32(v0, pb[ks], oacc0);
                oacc1 = mfma32(v1, pb[ks], oacc1);
            }
            __builtin_amdgcn_s_setprio(0);
        }
    }

    // ---- merge the two kv-halves (per q-subtile) via LDS ----
    __syncthreads();
    float* fb = reinterpret_cast<float*>(&Ks[0][0]) + qs * 2048;  // 8KB/qs
    if (wk == 1) {
#pragma unroll
        for (int rr = 0; rr < 16; ++rr) {
            fb[rr * 64 + l] = oacc0[rr];
            fb[(16 + rr) * 64 + l] = oacc1[rr];
        }
        Ms[qs][l] = m_s;
        Ls[qs][l] = l_s;
    }
    __syncthreads();
    if (wk == 0) {
        float m1 = Ms[qs][l], l1 = Ls[qs][l];
        float mstar = fmaxf(m_s, m1);
        float a0 = exp2f(m_s - mstar), a1 = exp2f(m1 - mstar);
        float inv = 1.0f / (l_s * a0 + l1 * a1);
        a0 *= inv;
        a1 *= inv;

        // merged O (bf16) transposed into stride-72 LDS buffer (in Vs; 16B
        // aligned rows, 4-way instead of 32-way banking on the 2B scatter
        // stores), then coalesced uint4 store to att.
        unsigned short* ob = &Vs[0][0] + qs * 2304;
#pragma unroll
        for (int rr = 0; rr < 16; ++rr) {
            int d0 = (rr & 3) + 8 * (rr >> 2) + 4 * hh;
            float v0 = oacc0[rr] * a0 + fb[rr * 64 + l] * a1;
            float v1 = oacc1[rr] * a0 + fb[(16 + rr) * 64 + l] * a1;
            ob[l32 * 72 + d0] = f32_to_bf16(v0);
            ob[l32 * 72 + 32 + d0] = f32_to_bf16(v1);
        }
        // same-wave DS ordering: writes retire before these reads issue
#pragma unroll
        for (int p = 0; p < 4; ++p) {
            int r = p * 8 + (l >> 3), c = (l & 7) * 8;
            uint4 v = *reinterpret_cast<const uint4*>(&ob[r * 72 + c]);
            *reinterpret_cast<uint4*>(
                &att[(size_t)(q0 + qs * 32 + r) * CDIM + h * HDIM + c]) = v;
        }
    }
}

// ---------------------------------------------------------------------------
extern "C" void kernel_launch(void* const* d_in, const int* in_sizes, int n_in,
                              void* d_out, int out_size, void* d_ws, size_t ws_size,
                              hipStream_t stream) {
    const float* x     = (const float*)d_in[0];
    const float* W_qkv = (const float*)d_in[1];
    const float* W_out = (const float*)d_in[2];
    float* out = (float*)d_out;

    char* ws = (char*)d_ws;
    unsigned short* xb    = (unsigned short*)(ws);
    unsigned short* wqkvb = (unsigned short*)(ws + 6291456);
    unsigned short* woutb = (unsigned short*)(ws + 9830400);
    unsigned short* qkvb  = (unsigned short*)(ws + 11010048);
    unsigned short* vtb   = (unsigned short*)(ws + 29884416);
    unsigned short* attb  = (unsigned short*)(ws + 36175872);

    // one fused cvt launch: x (3.15M), W_qkv (1.77M), W_out (0.59M)
    cvt3_f32_bf16<<<5376, 256, 0, stream>>>(
        x, TSEQ * CDIM, xb,
        W_qkv, QKVW * CDIM, wqkvb,
        W_out, CDIM * CDIM, woutb);

    // qkv = x @ W_qkv^T ; Q columns (<768) pre-scaled by 0.125*log2e.
    // V column-blocks (n0 >= 1536) write TRANSPOSED to vtb directly
    // (fused transpose_v). T=64 -> 2304 blocks = 9/CU (was 2.25/CU).
    gemm_nt_mfma<1, 1, 64><<<dim3(QKVW / 64, TSEQ / 64), 256, 0, stream>>>(
        xb, wqkvb, qkvb, TSEQ, QKVW, CDIM, CDIM, 0.125f * 1.44269504f, vtb);

    attn_mfma<<<dim3(NHEAD * (TSEQ / 64)), 256, 0, stream>>>(qkvb, vtb, attb);

    // out projection: T=64 tile -> 768 blocks (3/CU)
    gemm_nt_mfma<0, 0, 64><<<dim3(CDIM / 64, TSEQ / 64), 256, 0, stream>>>(
        attb, woutb, out, TSEQ, CDIM, CDIM, 0, 1.0f, nullptr);
}

// Round 16
// 110.448 us; speedup vs baseline: 1.0975x; 1.0975x over previous
//
#include <hip/hip_runtime.h>
#include <math.h>

typedef __bf16 bf16x8 __attribute__((ext_vector_type(8)));
typedef __bf16 bf16x2 __attribute__((ext_vector_type(2)));
typedef float f32x4 __attribute__((ext_vector_type(4)));
typedef float f32x16 __attribute__((ext_vector_type(16)));
typedef unsigned int u32x2 __attribute__((ext_vector_type(2)));

static constexpr int TSEQ = 4096;
static constexpr int CDIM = 768;
static constexpr int NHEAD = 12;
static constexpr int HDIM = 64;
static constexpr int QKVW = 2304;

__device__ inline unsigned short f32_to_bf16(float f) {
    unsigned int u = __builtin_bit_cast(unsigned int, f);
    u = (u + 0x7FFFu + ((u >> 16) & 1u)) >> 16;
    return (unsigned short)u;
}

__device__ inline f32x4 mfma16(bf16x8 a, bf16x8 b, f32x4 c) {
    return __builtin_amdgcn_mfma_f32_16x16x32_bf16(a, b, c, 0, 0, 0);
}

__device__ inline f32x16 mfma32(bf16x8 a, bf16x8 b, f32x16 c) {
    return __builtin_amdgcn_mfma_f32_32x32x16_bf16(a, b, c, 0, 0, 0);
}

// v_permlane32_swap_b32 via builtin (guaranteed two-result semantics):
// new_a[32:63] = old_b[0:31], new_b[0:31] = old_a[32:63].
__device__ inline void pls32(unsigned int &a, unsigned int &b) {
    u32x2 r = __builtin_amdgcn_permlane32_swap(a, b, false, false);
    a = r[0];
    b = r[1];
}

__device__ inline float swap_fmax(float x) {
    unsigned int a = __builtin_bit_cast(unsigned int, x), b = a;
    pls32(a, b);
    return fmaxf(__builtin_bit_cast(float, a), __builtin_bit_cast(float, b));
}

__device__ inline float swap_fadd(float x) {
    unsigned int a = __builtin_bit_cast(unsigned int, x), b = a;
    pls32(a, b);
    return __builtin_bit_cast(float, a) + __builtin_bit_cast(float, b);
}

__device__ inline unsigned int pkbf(float a, float b) {
    bf16x2 t;
    t[0] = (__bf16)a;
    t[1] = (__bf16)b;
    return __builtin_bit_cast(unsigned int, t);
}

#define GLOAD_LDS16(g, s)                                                        \
    __builtin_amdgcn_global_load_lds(                                            \
        (const __attribute__((address_space(1))) void*)(g),                      \
        (__attribute__((address_space(3))) void*)(s), 16, 0, 0)

// ---------------------------------------------------------------------------
// fused fp32 -> bf16 convert for x, W_qkv, W_out (one launch)
// ---------------------------------------------------------------------------
__global__ __launch_bounds__(256) void cvt3_f32_bf16(
    const float* __restrict__ a, int na, unsigned short* __restrict__ oa,
    const float* __restrict__ b, int nb, unsigned short* __restrict__ ob,
    const float* __restrict__ c, int nc, unsigned short* __restrict__ oc)
{
    int i = (blockIdx.x * 256 + threadIdx.x) * 4;
    const float* src;
    unsigned short* dst;
    if (i < na) {
        src = a + i; dst = oa + i;
    } else if ((i - na) < nb) {
        src = b + (i - na); dst = ob + (i - na);
    } else if ((i - na - nb) < nc) {
        src = c + (i - na - nb); dst = oc + (i - na - nb);
    } else {
        return;
    }
    float4 v = *reinterpret_cast<const float4*>(src);
    ushort4 o;
    o.x = f32_to_bf16(v.x); o.y = f32_to_bf16(v.y);
    o.z = f32_to_bf16(v.z); o.w = f32_to_bf16(v.w);
    *reinterpret_cast<ushort4*>(dst) = o;
}

// ---------------------------------------------------------------------------
// NT GEMM bf16 MFMA, tile T x T (T in {64,128}), BK=32, 4 waves (2x2),
// single-barrier double-buffered staging (verified round-13 schedule):
// per K-step { __syncthreads (drains stage(k) for all waves); issue
// stage(k+1) into other buffer (flight hidden under compute(k));
// compute(k) }.
// Round-16 (final): gemm1 back at T=128 (round-15's T=64 regressed ~11us:
// per-barrier MFMA count collapsed 16->4 while per-iter fixed cost was
// constant, and 4x blocks doubled L2 panel traffic -- per-block efficiency
// dominates over grid-quantization at >=2 blocks/CU). gemm2 stays T=64
// (verified round-14 win: its 0.75 blocks/CU grid left whole CUs idle).
// VT=1: blocks with n0 >= 1536 (V columns of the QKV GEMM) write their
// output TRANSPOSED to vt via an LDS bounce Ts[T][T+8] aliasing the
// staging buffers (barrier before reuse).
// ---------------------------------------------------------------------------
template <int OUT_BF16, int VT, int T>
__global__ __launch_bounds__(256) void gemm_nt_mfma(
    const unsigned short* __restrict__ A, const unsigned short* __restrict__ B,
    void* __restrict__ Cv, int M, int N, int K, int scale_cols, float scale,
    unsigned short* __restrict__ vt)
{
    // As dbuf [2][T][32] at 0, Bs dbuf [2][T][32] at 2*T*32 (elements).
    // VT epilogue reuses smem as Ts[T][T+8].
    constexpr int TB = T * 32;                  // one buffer, elements
    constexpr int TSZ = T * (T + 8);            // VT bounce, elements
    constexpr int SMEM = (VT && TSZ > 4 * TB) ? TSZ : 4 * TB;
    __shared__ unsigned short smem[SMEM];

    constexpr int NF = T / 32;                  // 16-wide frags per wave dim
    constexpr int NP = T / 64;                  // stage issues per matrix

    const int tid = threadIdx.x;
    const int w = tid >> 6, l = tid & 63;
    const int l16 = l & 15, lg = l >> 4;
    const int wy = w >> 1, wx = w & 1;
    const int m0 = blockIdx.y * T, n0 = blockIdx.x * T;
    const float cs = (n0 < scale_cols) ? scale : 1.0f;

    f32x4 acc[NF][NF];
#pragma unroll
    for (int i = 0; i < NF; ++i)
#pragma unroll
        for (int j = 0; j < NF; ++j) {
            f32x4 z = {0.f, 0.f, 0.f, 0.f};
            acc[i][j] = z;
        }

    const int lrow = l >> 2;
    const int lkb = (l & 3) * 8;

    // stage K-step k0 into buffer buf (A: Tx32, B: Tx32; 16B/lane x NP x2)
    auto stage = [&](int k0, int buf) {
#pragma unroll
        for (int p = 0; p < NP; ++p) {
            int c = w * NP + p;
            const unsigned short* ga = &A[(size_t)(m0 + c * 16 + lrow) * K + k0 + lkb];
            GLOAD_LDS16(ga, &smem[buf * TB + c * 16 * 32]);
            const unsigned short* gb = &B[(size_t)(n0 + c * 16 + lrow) * K + k0 + lkb];
            GLOAD_LDS16(gb, &smem[2 * TB + buf * TB + c * 16 * 32]);
        }
    };

    const int nk = K >> 5;
    stage(0, 0);

    for (int kk = 0; kk < nk; ++kk) {
        // drains stage(kk) (issued last iter / prologue) for all waves;
        // also fences compute(kk-1)'s ds_reads -> stage(kk+1) overwrite of
        // buffer (kk+1)&1 (last read at compute(kk-1)) is safe.
        __syncthreads();
        if (kk + 1 < nk) stage((kk + 1) * 32, (kk + 1) & 1);

        const unsigned short* as = &smem[(kk & 1) * TB];
        const unsigned short* bs = &smem[2 * TB + (kk & 1) * TB];
        bf16x8 af[NF], bf[NF];
#pragma unroll
        for (int i = 0; i < NF; ++i) {
            af[i] = *reinterpret_cast<const bf16x8*>(
                &as[(wy * (T / 2) + i * 16 + l16) * 32 + lg * 8]);
            bf[i] = *reinterpret_cast<const bf16x8*>(
                &bs[(wx * (T / 2) + i * 16 + l16) * 32 + lg * 8]);
        }
        __builtin_amdgcn_s_setprio(1);
#pragma unroll
        for (int i = 0; i < NF; ++i)
#pragma unroll
            for (int j = 0; j < NF; ++j)
                acc[i][j] = mfma16(af[i], bf[j], acc[i][j]);
        __builtin_amdgcn_s_setprio(0);
    }

    if (VT && n0 >= 1536) {
        // transposed epilogue: acc -> Ts[cc][rr] (chan-major, stride T+8),
        // then coalesced row stores to vt[(chan)*TSEQ + time]. Ts aliases
        // the staging buffers -> barrier before reuse.
        __syncthreads();
        unsigned short* Ts = &smem[0];
#pragma unroll
        for (int i = 0; i < NF; ++i)
#pragma unroll
            for (int j = 0; j < NF; ++j)
#pragma unroll
                for (int r = 0; r < 4; ++r) {
                    int rr = wy * (T / 2) + i * 16 + lg * 4 + r;
                    int cc = wx * (T / 2) + j * 16 + l16;
                    Ts[cc * (T + 8) + rr] = f32_to_bf16(acc[i][j][r]);
                }
        __syncthreads();
        constexpr int CH = T / 8;               // 16B chunks per row
#pragma unroll
        for (int p = 0; p < T * CH / 256; ++p) {
            int idx = p * 256 + tid;
            int row = idx / CH;                 // chan-rel 0..T-1
            int ch = idx % CH;                  // 16B chunk
            uint4 v = *reinterpret_cast<const uint4*>(
                &Ts[row * (T + 8) + ch * 8]);
            *reinterpret_cast<uint4*>(
                &vt[(size_t)(n0 - 1536 + row) * TSEQ + m0 + ch * 8]) = v;
        }
        return;
    }

#pragma unroll
    for (int i = 0; i < NF; ++i)
#pragma unroll
        for (int j = 0; j < NF; ++j)
#pragma unroll
            for (int r = 0; r < 4; ++r) {
                int row = m0 + wy * (T / 2) + i * 16 + lg * 4 + r;
                int col = n0 + wx * (T / 2) + j * 16 + l16;
                float v = acc[i][j][r] * cs;
                if (OUT_BF16)
                    ((unsigned short*)Cv)[(size_t)row * N + col] = f32_to_bf16(v);
                else
                    ((float*)Cv)[(size_t)row * N + col] = v;
            }
}

// ---------------------------------------------------------------------------
// Causal flash attention, 32x32x16 MFMA, swapped operands end-to-end:
//   S^T = mfma32(K, Q)  -> lane holds col q = l&31, rows = kv  (q lane-local)
//   O^T = mfma32(V^T, P)-> lane holds col q = l&31, rows = d   (q lane-local)
// Byte-identical to the verified round-10 optimum (73.9 us). Schedule
// (per KV tile, 2 barriers):
//   A: K(it) landed; PV(it-1) V-reads done  -> stageV(it) (hidden under
//      QK+softmax)  -> QK -> mask -> softmax
//   B: V(it) landed; QK K-reads done        -> stageK(it+1) (hidden under
//      pack+PV)     -> pack P -> PV
// Both K and V single-buffered; LDS read/stage addresses loop-invariant.
// Softmax: in-register max3 trees + one permlane32_swap; P->bf16 via cvt_pk
// pairs + permlane32_swap (T12); defer-max (T13, THR=8); exp2-domain
// (Q pre-scaled by 0.125*log2e in the QKV GEMM). T5 setprio on MFMA.
// 4 waves = 2 q-subtiles x 2 kv-halves, merged via LDS at the end.
// ---------------------------------------------------------------------------
__global__ __launch_bounds__(256, 3) void attn_mfma(
    const unsigned short* __restrict__ qkv,   // [4096][2304] bf16
    const unsigned short* __restrict__ vtg,   // [768][4096] bf16
    unsigned short* __restrict__ att)         // [4096][768] bf16
{
    __shared__ unsigned short Ks[2][64 * 64];   // [kv-half] single 16 KiB
    __shared__ unsigned short Vs[2][64 * 64];   // [kv-half] single 16 KiB
    __shared__ float Ms[2][64], Ls[2][64];

    const int b = blockIdx.x;
    const int h = b % NHEAD;
    const int qt = (TSEQ / 64 - 1) - b / NHEAD;   // LPT: heaviest first
    const int q0 = qt * 64;
    const int tid = threadIdx.x;
    const int w = tid >> 6, l = tid & 63;
    const int qs = w >> 1;        // q sub-block (32 rows)
    const int wk = w & 1;         // kv half
    const int l32 = l & 31, hh = l >> 5;

    const int NT = qt + 1;
    const int NH = NT >> 1;           // tiles in first half
    const int ITER = NT - NH;         // loop count (= second-half tiles)
    const int tbase = wk ? NH : 0;
    const int tcnt  = wk ? ITER : NH;

    // Q B-fragments: Q[q0+qs*32+l32][ks*16 + hh*8 .. +7], pre-scaled
    bf16x8 qf[4];
    {
        const unsigned short* qrow =
            &qkv[(size_t)(q0 + qs * 32 + l32) * QKVW + h * HDIM + hh * 8];
#pragma unroll
        for (int ks = 0; ks < 4; ++ks)
            qf[ks] = *reinterpret_cast<const bf16x8*>(qrow + ks * 16);
    }

    f32x16 oacc0, oacc1;
#pragma unroll
    for (int i = 0; i < 16; ++i) { oacc0[i] = 0.f; oacc1[i] = 0.f; }
    float m_s = -1e30f, l_s = 0.f;

    // loop-invariant zero accumulator (C operand of first QK mfma)
    f32x16 zf;
#pragma unroll
    for (int i = 0; i < 16; ++i) zf[i] = 0.f;

    // loop-invariant swizzled LDS read bases (element units)
    const int cx = l32 & 7;
    const unsigned short* kb8[4];
    const unsigned short* vb8[4];
#pragma unroll
    for (int ks = 0; ks < 4; ++ks) {
        const int sw = l32 * 64 + (((2 * ks + hh) ^ cx) * 8);
        kb8[ks] = &Ks[wk][sw];
        vb8[ks] = &Vs[wk][sw];
    }

    // stage K tile kt (64 kv-rows x 64 d, XOR-swizzled via pre-swizzled
    // global source, LDS linear) into Ks[wk]; 2 waves x 4 issues each.
    auto stageK = [&](int kt) {
#pragma unroll
        for (int i = 0; i < 4; ++i) {
            int u = i * 128 + qs * 64 + l;       // 16B unit in 8KB tile
            int r = u >> 3;
            int sc = (u & 7) ^ (r & 7);
            const unsigned short* g =
                &qkv[(size_t)(kt * 64 + r) * QKVW + CDIM + h * HDIM + sc * 8];
            GLOAD_LDS16(g, &Ks[wk][(i * 128 + qs * 64) * 8]);
        }
    };

    // stage V^T tile kt (64 d-rows x 64 kv, same swizzle; kv-contiguous
    // rows -> coalesced) into Vs[wk].
    auto stageV = [&](int kt) {
#pragma unroll
        for (int i = 0; i < 4; ++i) {
            int u = i * 128 + qs * 64 + l;       // 16B unit in 8KB tile
            int r = u >> 3;                      // d-row 0..63
            int sc = (u & 7) ^ (r & 7);          // swizzled kv-chunk
            const unsigned short* g =
                &vtg[(size_t)(h * HDIM + r) * TSEQ + kt * 64 + sc * 8];
            GLOAD_LDS16(g, &Vs[wk][(i * 128 + qs * 64) * 8]);
        }
    };

    if (tcnt > 0) stageK(tbase);

    for (int it = 0; it < ITER; ++it) {
        const bool act = it < tcnt;
        const int kt = tbase + it;

        // Barrier A: K(it) (staged after B(it-1) / prologue) landed for all
        // waves; PV(it-1) reads of Vs done -> V overwrite safe.
        __syncthreads();

        if (act) stageV(kt);     // lands during QK+softmax, checked at B

        f32x16 s0, s1;
        if (act) {
            // QK: S^T[kv][q], A = K rows from LDS, B = Q rows in regs
            __builtin_amdgcn_s_setprio(1);
            {
                bf16x8 k0 = *reinterpret_cast<const bf16x8*>(kb8[0]);
                bf16x8 k1 = *reinterpret_cast<const bf16x8*>(kb8[0] + 2048);
                s0 = mfma32(k0, qf[0], zf);
                s1 = mfma32(k1, qf[0], zf);
            }
#pragma unroll
            for (int ks = 1; ks < 4; ++ks) {
                bf16x8 k0 = *reinterpret_cast<const bf16x8*>(kb8[ks]);
                bf16x8 k1 = *reinterpret_cast<const bf16x8*>(kb8[ks] + 2048);
                s0 = mfma32(k0, qf[ks], s0);
                s1 = mfma32(k1, qf[ks], s1);
            }
            __builtin_amdgcn_s_setprio(0);

            // causal mask (diag tile only; always in second half)
            if (kt == qt) {
                const int qq = qs * 32 + l32;
#pragma unroll
                for (int rr = 0; rr < 16; ++rr) {
                    int kv0 = (rr & 3) + 8 * (rr >> 2) + 4 * hh;
                    if (kv0 > qq) s0[rr] = -1e30f;
                    if (kv0 + 32 > qq) s1[rr] = -1e30f;
                }
            }

            // ---- online softmax, q lane-local (v_max3 tree) ----
            float ma = fmaxf(fmaxf(s0[0], s0[1]), s0[2]);
            float mb = fmaxf(fmaxf(s0[3], s0[4]), s0[5]);
            float mc = fmaxf(fmaxf(s0[6], s0[7]), s0[8]);
            float md = fmaxf(fmaxf(s0[9], s0[10]), s0[11]);
            float me = fmaxf(fmaxf(s0[12], s0[13]), s0[14]);
            float mf = fmaxf(fmaxf(s0[15], s1[0]), s1[1]);
            float mg = fmaxf(fmaxf(s1[2], s1[3]), s1[4]);
            float mh = fmaxf(fmaxf(s1[5], s1[6]), s1[7]);
            float mi = fmaxf(fmaxf(s1[8], s1[9]), s1[10]);
            float mj = fmaxf(fmaxf(s1[11], s1[12]), s1[13]);
            float mk = fmaxf(s1[14], s1[15]);
            ma = fmaxf(fmaxf(ma, mb), mc);
            md = fmaxf(fmaxf(md, me), mf);
            mg = fmaxf(fmaxf(mg, mh), mi);
            mj = fmaxf(mj, mk);
            float mx = fmaxf(fmaxf(ma, md), fmaxf(mg, mj));
            mx = swap_fmax(mx);

            if (!__all(mx <= m_s + 8.0f)) {        // T13 defer-max
                float mnew = fmaxf(m_s, mx);
                float alpha = exp2f(m_s - mnew);
                m_s = mnew;
                l_s *= alpha;
#pragma unroll
                for (int i = 0; i < 16; ++i) {
                    oacc0[i] *= alpha;
                    oacc1[i] *= alpha;
                }
            }

#pragma unroll
            for (int i = 0; i < 16; ++i) {
                s0[i] = exp2f(s0[i] - m_s);
                s1[i] = exp2f(s1[i] - m_s);
            }
            float ts = 0.f;
#pragma unroll
            for (int i = 0; i < 16; ++i) ts += s0[i] + s1[i];
            l_s += swap_fadd(ts);
        }

        // Barrier B: V(it) landed + visible; all QK reads of Ks done, so
        // stageK(it+1) below may overwrite the single K buffer. Its flight
        // is hidden under pack+PV and drained by the next barrier A.
        __syncthreads();

        if (it + 1 < tcnt) stageK(tbase + it + 1);

        if (act) {
            // ---- pack P to PV B-fragments (T12: cvt_pk + permlane32_swap)
            // k-group ks (16 kv): lane needs P[q=l32][kv = ks*16 + hh*8 + j]
            bf16x8 pb[4];
#pragma unroll
            for (int ks = 0; ks < 4; ++ks) {
                const int r0 = (ks & 1) * 8;
                unsigned int w0, w1, w2, w3;
                if (ks < 2) {
                    w0 = pkbf(s0[r0 + 0], s0[r0 + 1]);
                    w1 = pkbf(s0[r0 + 2], s0[r0 + 3]);
                    w2 = pkbf(s0[r0 + 4], s0[r0 + 5]);
                    w3 = pkbf(s0[r0 + 6], s0[r0 + 7]);
                } else {
                    w0 = pkbf(s1[r0 + 0], s1[r0 + 1]);
                    w1 = pkbf(s1[r0 + 2], s1[r0 + 3]);
                    w2 = pkbf(s1[r0 + 4], s1[r0 + 5]);
                    w3 = pkbf(s1[r0 + 6], s1[r0 + 7]);
                }
                pls32(w0, w2);
                pls32(w1, w3);
                uint4 uv = make_uint4(w0, w1, w2, w3);
                pb[ks] = __builtin_bit_cast(bf16x8, uv);
            }

            // ---- O^T += V^T P : V fragments from LDS (invariant addrs)
            __builtin_amdgcn_s_setprio(1);
#pragma unroll
            for (int ks = 0; ks < 4; ++ks) {
                bf16x8 v0 = *reinterpret_cast<const bf16x8*>(vb8[ks]);
                bf16x8 v1 = *reinterpret_cast<const bf16x8*>(vb8[ks] + 2048);
                oacc0 = mfma32(v0, pb[ks], oacc0);
                oacc1 = mfma32(v1, pb[ks], oacc1);
            }
            __builtin_amdgcn_s_setprio(0);
        }
    }

    // ---- merge the two kv-halves (per q-subtile) via LDS ----
    __syncthreads();
    float* fb = reinterpret_cast<float*>(&Ks[0][0]) + qs * 2048;  // 8KB/qs
    if (wk == 1) {
#pragma unroll
        for (int rr = 0; rr < 16; ++rr) {
            fb[rr * 64 + l] = oacc0[rr];
            fb[(16 + rr) * 64 + l] = oacc1[rr];
        }
        Ms[qs][l] = m_s;
        Ls[qs][l] = l_s;
    }
    __syncthreads();
    if (wk == 0) {
        float m1 = Ms[qs][l], l1 = Ls[qs][l];
        float mstar = fmaxf(m_s, m1);
        float a0 = exp2f(m_s - mstar), a1 = exp2f(m1 - mstar);
        float inv = 1.0f / (l_s * a0 + l1 * a1);
        a0 *= inv;
        a1 *= inv;

        // merged O (bf16) transposed into stride-72 LDS buffer (in Vs; 16B
        // aligned rows, 4-way instead of 32-way banking on the 2B scatter
        // stores), then coalesced uint4 store to att.
        unsigned short* ob = &Vs[0][0] + qs * 2304;
#pragma unroll
        for (int rr = 0; rr < 16; ++rr) {
            int d0 = (rr & 3) + 8 * (rr >> 2) + 4 * hh;
            float v0 = oacc0[rr] * a0 + fb[rr * 64 + l] * a1;
            float v1 = oacc1[rr] * a0 + fb[(16 + rr) * 64 + l] * a1;
            ob[l32 * 72 + d0] = f32_to_bf16(v0);
            ob[l32 * 72 + 32 + d0] = f32_to_bf16(v1);
        }
        // same-wave DS ordering: writes retire before these reads issue
#pragma unroll
        for (int p = 0; p < 4; ++p) {
            int r = p * 8 + (l >> 3), c = (l & 7) * 8;
            uint4 v = *reinterpret_cast<const uint4*>(&ob[r * 72 + c]);
            *reinterpret_cast<uint4*>(
                &att[(size_t)(q0 + qs * 32 + r) * CDIM + h * HDIM + c]) = v;
        }
    }
}

// ---------------------------------------------------------------------------
extern "C" void kernel_launch(void* const* d_in, const int* in_sizes, int n_in,
                              void* d_out, int out_size, void* d_ws, size_t ws_size,
                              hipStream_t stream) {
    const float* x     = (const float*)d_in[0];
    const float* W_qkv = (const float*)d_in[1];
    const float* W_out = (const float*)d_in[2];
    float* out = (float*)d_out;

    char* ws = (char*)d_ws;
    unsigned short* xb    = (unsigned short*)(ws);
    unsigned short* wqkvb = (unsigned short*)(ws + 6291456);
    unsigned short* woutb = (unsigned short*)(ws + 9830400);
    unsigned short* qkvb  = (unsigned short*)(ws + 11010048);
    unsigned short* vtb   = (unsigned short*)(ws + 29884416);
    unsigned short* attb  = (unsigned short*)(ws + 36175872);

    // one fused cvt launch: x (3.15M), W_qkv (1.77M), W_out (0.59M)
    cvt3_f32_bf16<<<5376, 256, 0, stream>>>(
        x, TSEQ * CDIM, xb,
        W_qkv, QKVW * CDIM, wqkvb,
        W_out, CDIM * CDIM, woutb);

    // qkv = x @ W_qkv^T ; Q columns (<768) pre-scaled by 0.125*log2e.
    // V column-blocks (n0 >= 1536) write TRANSPOSED to vtb directly
    // (fused transpose_v). T=128 (round-14 optimum; T=64 falsified r15).
    gemm_nt_mfma<1, 1, 128><<<dim3(QKVW / 128, TSEQ / 128), 256, 0, stream>>>(
        xb, wqkvb, qkvb, TSEQ, QKVW, CDIM, CDIM, 0.125f * 1.44269504f, vtb);

    attn_mfma<<<dim3(NHEAD * (TSEQ / 64)), 256, 0, stream>>>(qkvb, vtb, attb);

    // out projection: T=64 tile -> 768 blocks (3/CU; r14 verified win)
    gemm_nt_mfma<0, 0, 64><<<dim3(CDIM / 64, TSEQ / 64), 256, 0, stream>>>(
        attb, woutb, out, TSEQ, CDIM, CDIM, 0, 1.0f, nullptr);
}

// Round 17
// 108.908 us; speedup vs baseline: 1.1131x; 1.0141x over previous
//
#include <hip/hip_runtime.h>
#include <math.h>

typedef __bf16 bf16x8 __attribute__((ext_vector_type(8)));
typedef __bf16 bf16x2 __attribute__((ext_vector_type(2)));
typedef float f32x4 __attribute__((ext_vector_type(4)));
typedef float f32x16 __attribute__((ext_vector_type(16)));
typedef unsigned int u32x2 __attribute__((ext_vector_type(2)));

static constexpr int TSEQ = 4096;
static constexpr int CDIM = 768;
static constexpr int NHEAD = 12;
static constexpr int HDIM = 64;
static constexpr int QKVW = 2304;

__device__ inline unsigned short f32_to_bf16(float f) {
    unsigned int u = __builtin_bit_cast(unsigned int, f);
    u = (u + 0x7FFFu + ((u >> 16) & 1u)) >> 16;
    return (unsigned short)u;
}

__device__ inline f32x4 mfma16(bf16x8 a, bf16x8 b, f32x4 c) {
    return __builtin_amdgcn_mfma_f32_16x16x32_bf16(a, b, c, 0, 0, 0);
}

__device__ inline f32x16 mfma32(bf16x8 a, bf16x8 b, f32x16 c) {
    return __builtin_amdgcn_mfma_f32_32x32x16_bf16(a, b, c, 0, 0, 0);
}

// v_permlane32_swap_b32 via builtin (guaranteed two-result semantics):
// new_a[32:63] = old_b[0:31], new_b[0:31] = old_a[32:63].
__device__ inline void pls32(unsigned int &a, unsigned int &b) {
    u32x2 r = __builtin_amdgcn_permlane32_swap(a, b, false, false);
    a = r[0];
    b = r[1];
}

__device__ inline float swap_fmax(float x) {
    unsigned int a = __builtin_bit_cast(unsigned int, x), b = a;
    pls32(a, b);
    return fmaxf(__builtin_bit_cast(float, a), __builtin_bit_cast(float, b));
}

__device__ inline float swap_fadd(float x) {
    unsigned int a = __builtin_bit_cast(unsigned int, x), b = a;
    pls32(a, b);
    return __builtin_bit_cast(float, a) + __builtin_bit_cast(float, b);
}

__device__ inline unsigned int pkbf(float a, float b) {
    bf16x2 t;
    t[0] = (__bf16)a;
    t[1] = (__bf16)b;
    return __builtin_bit_cast(unsigned int, t);
}

#define GLOAD_LDS16(g, s)                                                        \
    __builtin_amdgcn_global_load_lds(                                            \
        (const __attribute__((address_space(1))) void*)(g),                      \
        (__attribute__((address_space(3))) void*)(s), 16, 0, 0)

// ---------------------------------------------------------------------------
// fused fp32 -> bf16 convert for x, W_qkv, W_out (one launch)
// ---------------------------------------------------------------------------
__global__ __launch_bounds__(256) void cvt3_f32_bf16(
    const float* __restrict__ a, int na, unsigned short* __restrict__ oa,
    const float* __restrict__ b, int nb, unsigned short* __restrict__ ob,
    const float* __restrict__ c, int nc, unsigned short* __restrict__ oc)
{
    int i = (blockIdx.x * 256 + threadIdx.x) * 4;
    const float* src;
    unsigned short* dst;
    if (i < na) {
        src = a + i; dst = oa + i;
    } else if ((i - na) < nb) {
        src = b + (i - na); dst = ob + (i - na);
    } else if ((i - na - nb) < nc) {
        src = c + (i - na - nb); dst = oc + (i - na - nb);
    } else {
        return;
    }
    float4 v = *reinterpret_cast<const float4*>(src);
    ushort4 o;
    o.x = f32_to_bf16(v.x); o.y = f32_to_bf16(v.y);
    o.z = f32_to_bf16(v.z); o.w = f32_to_bf16(v.w);
    *reinterpret_cast<ushort4*>(dst) = o;
}

// ---------------------------------------------------------------------------
// NT GEMM bf16 MFMA, tile T x T (T in {64,128}), BK=32, 4 waves (2x2),
// single-barrier double-buffered staging (verified round-13 schedule):
// per K-step { __syncthreads (drains stage(k) for all waves); issue
// stage(k+1) into other buffer (flight hidden under compute(k));
// compute(k) }.
// Round-17: T1 XCD-chunked block swizzle. Default x-major dispatch
// round-robins consecutive blocks (which share a T x K A-row-panel) across
// the 8 XCD L2s, so every XCD refetches both panels from L3. Bijective
// remap swz = (lin&7)*(nwg/8) + lin>>3 (both grids %8==0) gives each XCD a
// contiguous chunk: all its A/B panels fit its 4MB L2 with 18x/4x reuse.
// Work is uniform per block -> no LPT interaction (unlike attn's r7).
// gemm1 T=128 (r15's T=64 falsified: per-barrier MFMA collapsed 16->4);
// gemm2 T=64 (r14 verified: 0.75 blocks/CU grid left whole CUs idle).
// VT=1: blocks with n0 >= 1536 (V columns of the QKV GEMM) write their
// output TRANSPOSED to vt via an LDS bounce Ts[T][T+8] aliasing the
// staging buffers (barrier before reuse).
// ---------------------------------------------------------------------------
template <int OUT_BF16, int VT, int T>
__global__ __launch_bounds__(256) void gemm_nt_mfma(
    const unsigned short* __restrict__ A, const unsigned short* __restrict__ B,
    void* __restrict__ Cv, int M, int N, int K, int scale_cols, float scale,
    unsigned short* __restrict__ vt)
{
    // As dbuf [2][T][32] at 0, Bs dbuf [2][T][32] at 2*T*32 (elements).
    // VT epilogue reuses smem as Ts[T][T+8].
    constexpr int TB = T * 32;                  // one buffer, elements
    constexpr int TSZ = T * (T + 8);            // VT bounce, elements
    constexpr int SMEM = (VT && TSZ > 4 * TB) ? TSZ : 4 * TB;
    __shared__ unsigned short smem[SMEM];

    constexpr int NF = T / 32;                  // 16-wide frags per wave dim
    constexpr int NP = T / 64;                  // stage issues per matrix

    const int tid = threadIdx.x;
    const int w = tid >> 6, l = tid & 63;
    const int l16 = l & 15, lg = l >> 4;
    const int wy = w >> 1, wx = w & 1;

    // T1: XCD-chunked bijective remap (dispatch index lin is x-major).
    const int nbx = gridDim.x;
    const int lin = blockIdx.y * nbx + blockIdx.x;
    const int cpx = (nbx * gridDim.y) >> 3;     // blocks per XCD chunk
    const int swz = (lin & 7) * cpx + (lin >> 3);
    const int m0 = (swz / nbx) * T, n0 = (swz % nbx) * T;
    const float cs = (n0 < scale_cols) ? scale : 1.0f;

    f32x4 acc[NF][NF];
#pragma unroll
    for (int i = 0; i < NF; ++i)
#pragma unroll
        for (int j = 0; j < NF; ++j) {
            f32x4 z = {0.f, 0.f, 0.f, 0.f};
            acc[i][j] = z;
        }

    const int lrow = l >> 2;
    const int lkb = (l & 3) * 8;

    // stage K-step k0 into buffer buf (A: Tx32, B: Tx32; 16B/lane x NP x2)
    auto stage = [&](int k0, int buf) {
#pragma unroll
        for (int p = 0; p < NP; ++p) {
            int c = w * NP + p;
            const unsigned short* ga = &A[(size_t)(m0 + c * 16 + lrow) * K + k0 + lkb];
            GLOAD_LDS16(ga, &smem[buf * TB + c * 16 * 32]);
            const unsigned short* gb = &B[(size_t)(n0 + c * 16 + lrow) * K + k0 + lkb];
            GLOAD_LDS16(gb, &smem[2 * TB + buf * TB + c * 16 * 32]);
        }
    };

    const int nk = K >> 5;
    stage(0, 0);

    for (int kk = 0; kk < nk; ++kk) {
        // drains stage(kk) (issued last iter / prologue) for all waves;
        // also fences compute(kk-1)'s ds_reads -> stage(kk+1) overwrite of
        // buffer (kk+1)&1 (last read at compute(kk-1)) is safe.
        __syncthreads();
        if (kk + 1 < nk) stage((kk + 1) * 32, (kk + 1) & 1);

        const unsigned short* as = &smem[(kk & 1) * TB];
        const unsigned short* bs = &smem[2 * TB + (kk & 1) * TB];
        bf16x8 af[NF], bf[NF];
#pragma unroll
        for (int i = 0; i < NF; ++i) {
            af[i] = *reinterpret_cast<const bf16x8*>(
                &as[(wy * (T / 2) + i * 16 + l16) * 32 + lg * 8]);
            bf[i] = *reinterpret_cast<const bf16x8*>(
                &bs[(wx * (T / 2) + i * 16 + l16) * 32 + lg * 8]);
        }
        __builtin_amdgcn_s_setprio(1);
#pragma unroll
        for (int i = 0; i < NF; ++i)
#pragma unroll
            for (int j = 0; j < NF; ++j)
                acc[i][j] = mfma16(af[i], bf[j], acc[i][j]);
        __builtin_amdgcn_s_setprio(0);
    }

    if (VT && n0 >= 1536) {
        // transposed epilogue: acc -> Ts[cc][rr] (chan-major, stride T+8),
        // then coalesced row stores to vt[(chan)*TSEQ + time]. Ts aliases
        // the staging buffers -> barrier before reuse.
        __syncthreads();
        unsigned short* Ts = &smem[0];
#pragma unroll
        for (int i = 0; i < NF; ++i)
#pragma unroll
            for (int j = 0; j < NF; ++j)
#pragma unroll
                for (int r = 0; r < 4; ++r) {
                    int rr = wy * (T / 2) + i * 16 + lg * 4 + r;
                    int cc = wx * (T / 2) + j * 16 + l16;
                    Ts[cc * (T + 8) + rr] = f32_to_bf16(acc[i][j][r]);
                }
        __syncthreads();
        constexpr int CH = T / 8;               // 16B chunks per row
#pragma unroll
        for (int p = 0; p < T * CH / 256; ++p) {
            int idx = p * 256 + tid;
            int row = idx / CH;                 // chan-rel 0..T-1
            int ch = idx % CH;                  // 16B chunk
            uint4 v = *reinterpret_cast<const uint4*>(
                &Ts[row * (T + 8) + ch * 8]);
            *reinterpret_cast<uint4*>(
                &vt[(size_t)(n0 - 1536 + row) * TSEQ + m0 + ch * 8]) = v;
        }
        return;
    }

#pragma unroll
    for (int i = 0; i < NF; ++i)
#pragma unroll
        for (int j = 0; j < NF; ++j)
#pragma unroll
            for (int r = 0; r < 4; ++r) {
                int row = m0 + wy * (T / 2) + i * 16 + lg * 4 + r;
                int col = n0 + wx * (T / 2) + j * 16 + l16;
                float v = acc[i][j][r] * cs;
                if (OUT_BF16)
                    ((unsigned short*)Cv)[(size_t)row * N + col] = f32_to_bf16(v);
                else
                    ((float*)Cv)[(size_t)row * N + col] = v;
            }
}

// ---------------------------------------------------------------------------
// Causal flash attention, 32x32x16 MFMA, swapped operands end-to-end:
//   S^T = mfma32(K, Q)  -> lane holds col q = l&31, rows = kv  (q lane-local)
//   O^T = mfma32(V^T, P)-> lane holds col q = l&31, rows = d   (q lane-local)
// Byte-identical to the verified round-10 optimum (73.9 us). Schedule
// (per KV tile, 2 barriers):
//   A: K(it) landed; PV(it-1) V-reads done  -> stageV(it) (hidden under
//      QK+softmax)  -> QK -> mask -> softmax
//   B: V(it) landed; QK K-reads done        -> stageK(it+1) (hidden under
//      pack+PV)     -> pack P -> PV
// Both K and V single-buffered; LDS read/stage addresses loop-invariant.
// Softmax: in-register max3 trees + one permlane32_swap; P->bf16 via cvt_pk
// pairs + permlane32_swap (T12); defer-max (T13, THR=8); exp2-domain
// (Q pre-scaled by 0.125*log2e in the QKV GEMM). T5 setprio on MFMA.
// 4 waves = 2 q-subtiles x 2 kv-halves, merged via LDS at the end.
// ---------------------------------------------------------------------------
__global__ __launch_bounds__(256, 3) void attn_mfma(
    const unsigned short* __restrict__ qkv,   // [4096][2304] bf16
    const unsigned short* __restrict__ vtg,   // [768][4096] bf16
    unsigned short* __restrict__ att)         // [4096][768] bf16
{
    __shared__ unsigned short Ks[2][64 * 64];   // [kv-half] single 16 KiB
    __shared__ unsigned short Vs[2][64 * 64];   // [kv-half] single 16 KiB
    __shared__ float Ms[2][64], Ls[2][64];

    const int b = blockIdx.x;
    const int h = b % NHEAD;
    const int qt = (TSEQ / 64 - 1) - b / NHEAD;   // LPT: heaviest first
    const int q0 = qt * 64;
    const int tid = threadIdx.x;
    const int w = tid >> 6, l = tid & 63;
    const int qs = w >> 1;        // q sub-block (32 rows)
    const int wk = w & 1;         // kv half
    const int l32 = l & 31, hh = l >> 5;

    const int NT = qt + 1;
    const int NH = NT >> 1;           // tiles in first half
    const int ITER = NT - NH;         // loop count (= second-half tiles)
    const int tbase = wk ? NH : 0;
    const int tcnt  = wk ? ITER : NH;

    // Q B-fragments: Q[q0+qs*32+l32][ks*16 + hh*8 .. +7], pre-scaled
    bf16x8 qf[4];
    {
        const unsigned short* qrow =
            &qkv[(size_t)(q0 + qs * 32 + l32) * QKVW + h * HDIM + hh * 8];
#pragma unroll
        for (int ks = 0; ks < 4; ++ks)
            qf[ks] = *reinterpret_cast<const bf16x8*>(qrow + ks * 16);
    }

    f32x16 oacc0, oacc1;
#pragma unroll
    for (int i = 0; i < 16; ++i) { oacc0[i] = 0.f; oacc1[i] = 0.f; }
    float m_s = -1e30f, l_s = 0.f;

    // loop-invariant zero accumulator (C operand of first QK mfma)
    f32x16 zf;
#pragma unroll
    for (int i = 0; i < 16; ++i) zf[i] = 0.f;

    // loop-invariant swizzled LDS read bases (element units)
    const int cx = l32 & 7;
    const unsigned short* kb8[4];
    const unsigned short* vb8[4];
#pragma unroll
    for (int ks = 0; ks < 4; ++ks) {
        const int sw = l32 * 64 + (((2 * ks + hh) ^ cx) * 8);
        kb8[ks] = &Ks[wk][sw];
        vb8[ks] = &Vs[wk][sw];
    }

    // stage K tile kt (64 kv-rows x 64 d, XOR-swizzled via pre-swizzled
    // global source, LDS linear) into Ks[wk]; 2 waves x 4 issues each.
    auto stageK = [&](int kt) {
#pragma unroll
        for (int i = 0; i < 4; ++i) {
            int u = i * 128 + qs * 64 + l;       // 16B unit in 8KB tile
            int r = u >> 3;
            int sc = (u & 7) ^ (r & 7);
            const unsigned short* g =
                &qkv[(size_t)(kt * 64 + r) * QKVW + CDIM + h * HDIM + sc * 8];
            GLOAD_LDS16(g, &Ks[wk][(i * 128 + qs * 64) * 8]);
        }
    };

    // stage V^T tile kt (64 d-rows x 64 kv, same swizzle; kv-contiguous
    // rows -> coalesced) into Vs[wk].
    auto stageV = [&](int kt) {
#pragma unroll
        for (int i = 0; i < 4; ++i) {
            int u = i * 128 + qs * 64 + l;       // 16B unit in 8KB tile
            int r = u >> 3;                      // d-row 0..63
            int sc = (u & 7) ^ (r & 7);          // swizzled kv-chunk
            const unsigned short* g =
                &vtg[(size_t)(h * HDIM + r) * TSEQ + kt * 64 + sc * 8];
            GLOAD_LDS16(g, &Vs[wk][(i * 128 + qs * 64) * 8]);
        }
    };

    if (tcnt > 0) stageK(tbase);

    for (int it = 0; it < ITER; ++it) {
        const bool act = it < tcnt;
        const int kt = tbase + it;

        // Barrier A: K(it) (staged after B(it-1) / prologue) landed for all
        // waves; PV(it-1) reads of Vs done -> V overwrite safe.
        __syncthreads();

        if (act) stageV(kt);     // lands during QK+softmax, checked at B

        f32x16 s0, s1;
        if (act) {
            // QK: S^T[kv][q], A = K rows from LDS, B = Q rows in regs
            __builtin_amdgcn_s_setprio(1);
            {
                bf16x8 k0 = *reinterpret_cast<const bf16x8*>(kb8[0]);
                bf16x8 k1 = *reinterpret_cast<const bf16x8*>(kb8[0] + 2048);
                s0 = mfma32(k0, qf[0], zf);
                s1 = mfma32(k1, qf[0], zf);
            }
#pragma unroll
            for (int ks = 1; ks < 4; ++ks) {
                bf16x8 k0 = *reinterpret_cast<const bf16x8*>(kb8[ks]);
                bf16x8 k1 = *reinterpret_cast<const bf16x8*>(kb8[ks] + 2048);
                s0 = mfma32(k0, qf[ks], s0);
                s1 = mfma32(k1, qf[ks], s1);
            }
            __builtin_amdgcn_s_setprio(0);

            // causal mask (diag tile only; always in second half)
            if (kt == qt) {
                const int qq = qs * 32 + l32;
#pragma unroll
                for (int rr = 0; rr < 16; ++rr) {
                    int kv0 = (rr & 3) + 8 * (rr >> 2) + 4 * hh;
                    if (kv0 > qq) s0[rr] = -1e30f;
                    if (kv0 + 32 > qq) s1[rr] = -1e30f;
                }
            }

            // ---- online softmax, q lane-local (v_max3 tree) ----
            float ma = fmaxf(fmaxf(s0[0], s0[1]), s0[2]);
            float mb = fmaxf(fmaxf(s0[3], s0[4]), s0[5]);
            float mc = fmaxf(fmaxf(s0[6], s0[7]), s0[8]);
            float md = fmaxf(fmaxf(s0[9], s0[10]), s0[11]);
            float me = fmaxf(fmaxf(s0[12], s0[13]), s0[14]);
            float mf = fmaxf(fmaxf(s0[15], s1[0]), s1[1]);
            float mg = fmaxf(fmaxf(s1[2], s1[3]), s1[4]);
            float mh = fmaxf(fmaxf(s1[5], s1[6]), s1[7]);
            float mi = fmaxf(fmaxf(s1[8], s1[9]), s1[10]);
            float mj = fmaxf(fmaxf(s1[11], s1[12]), s1[13]);
            float mk = fmaxf(s1[14], s1[15]);
            ma = fmaxf(fmaxf(ma, mb), mc);
            md = fmaxf(fmaxf(md, me), mf);
            mg = fmaxf(fmaxf(mg, mh), mi);
            mj = fmaxf(mj, mk);
            float mx = fmaxf(fmaxf(ma, md), fmaxf(mg, mj));
            mx = swap_fmax(mx);

            if (!__all(mx <= m_s + 8.0f)) {        // T13 defer-max
                float mnew = fmaxf(m_s, mx);
                float alpha = exp2f(m_s - mnew);
                m_s = mnew;
                l_s *= alpha;
#pragma unroll
                for (int i = 0; i < 16; ++i) {
                    oacc0[i] *= alpha;
                    oacc1[i] *= alpha;
                }
            }

#pragma unroll
            for (int i = 0; i < 16; ++i) {
                s0[i] = exp2f(s0[i] - m_s);
                s1[i] = exp2f(s1[i] - m_s);
            }
            float ts = 0.f;
#pragma unroll
            for (int i = 0; i < 16; ++i) ts += s0[i] + s1[i];
            l_s += swap_fadd(ts);
        }

        // Barrier B: V(it) landed + visible; all QK reads of Ks done, so
        // stageK(it+1) below may overwrite the single K buffer. Its flight
        // is hidden under pack+PV and drained by the next barrier A.
        __syncthreads();

        if (it + 1 < tcnt) stageK(tbase + it + 1);

        if (act) {
            // ---- pack P to PV B-fragments (T12: cvt_pk + permlane32_swap)
            // k-group ks (16 kv): lane needs P[q=l32][kv = ks*16 + hh*8 + j]
            bf16x8 pb[4];
#pragma unroll
            for (int ks = 0; ks < 4; ++ks) {
                const int r0 = (ks & 1) * 8;
                unsigned int w0, w1, w2, w3;
                if (ks < 2) {
                    w0 = pkbf(s0[r0 + 0], s0[r0 + 1]);
                    w1 = pkbf(s0[r0 + 2], s0[r0 + 3]);
                    w2 = pkbf(s0[r0 + 4], s0[r0 + 5]);
                    w3 = pkbf(s0[r0 + 6], s0[r0 + 7]);
                } else {
                    w0 = pkbf(s1[r0 + 0], s1[r0 + 1]);
                    w1 = pkbf(s1[r0 + 2], s1[r0 + 3]);
                    w2 = pkbf(s1[r0 + 4], s1[r0 + 5]);
                    w3 = pkbf(s1[r0 + 6], s1[r0 + 7]);
                }
                pls32(w0, w2);
                pls32(w1, w3);
                uint4 uv = make_uint4(w0, w1, w2, w3);
                pb[ks] = __builtin_bit_cast(bf16x8, uv);
            }

            // ---- O^T += V^T P : V fragments from LDS (invariant addrs)
            __builtin_amdgcn_s_setprio(1);
#pragma unroll
            for (int ks = 0; ks < 4; ++ks) {
                bf16x8 v0 = *reinterpret_cast<const bf16x8*>(vb8[ks]);
                bf16x8 v1 = *reinterpret_cast<const bf16x8*>(vb8[ks] + 2048);
                oacc0 = mfma32(v0, pb[ks], oacc0);
                oacc1 = mfma32(v1, pb[ks], oacc1);
            }
            __builtin_amdgcn_s_setprio(0);
        }
    }

    // ---- merge the two kv-halves (per q-subtile) via LDS ----
    __syncthreads();
    float* fb = reinterpret_cast<float*>(&Ks[0][0]) + qs * 2048;  // 8KB/qs
    if (wk == 1) {
#pragma unroll
        for (int rr = 0; rr < 16; ++rr) {
            fb[rr * 64 + l] = oacc0[rr];
            fb[(16 + rr) * 64 + l] = oacc1[rr];
        }
        Ms[qs][l] = m_s;
        Ls[qs][l] = l_s;
    }
    __syncthreads();
    if (wk == 0) {
        float m1 = Ms[qs][l], l1 = Ls[qs][l];
        float mstar = fmaxf(m_s, m1);
        float a0 = exp2f(m_s - mstar), a1 = exp2f(m1 - mstar);
        float inv = 1.0f / (l_s * a0 + l1 * a1);
        a0 *= inv;
        a1 *= inv;

        // merged O (bf16) transposed into stride-72 LDS buffer (in Vs; 16B
        // aligned rows, 4-way instead of 32-way banking on the 2B scatter
        // stores), then coalesced uint4 store to att.
        unsigned short* ob = &Vs[0][0] + qs * 2304;
#pragma unroll
        for (int rr = 0; rr < 16; ++rr) {
            int d0 = (rr & 3) + 8 * (rr >> 2) + 4 * hh;
            float v0 = oacc0[rr] * a0 + fb[rr * 64 + l] * a1;
            float v1 = oacc1[rr] * a0 + fb[(16 + rr) * 64 + l] * a1;
            ob[l32 * 72 + d0] = f32_to_bf16(v0);
            ob[l32 * 72 + 32 + d0] = f32_to_bf16(v1);
        }
        // same-wave DS ordering: writes retire before these reads issue
#pragma unroll
        for (int p = 0; p < 4; ++p) {
            int r = p * 8 + (l >> 3), c = (l & 7) * 8;
            uint4 v = *reinterpret_cast<const uint4*>(&ob[r * 72 + c]);
            *reinterpret_cast<uint4*>(
                &att[(size_t)(q0 + qs * 32 + r) * CDIM + h * HDIM + c]) = v;
        }
    }
}

// ---------------------------------------------------------------------------
extern "C" void kernel_launch(void* const* d_in, const int* in_sizes, int n_in,
                              void* d_out, int out_size, void* d_ws, size_t ws_size,
                              hipStream_t stream) {
    const float* x     = (const float*)d_in[0];
    const float* W_qkv = (const float*)d_in[1];
    const float* W_out = (const float*)d_in[2];
    float* out = (float*)d_out;

    char* ws = (char*)d_ws;
    unsigned short* xb    = (unsigned short*)(ws);
    unsigned short* wqkvb = (unsigned short*)(ws + 6291456);
    unsigned short* woutb = (unsigned short*)(ws + 9830400);
    unsigned short* qkvb  = (unsigned short*)(ws + 11010048);
    unsigned short* vtb   = (unsigned short*)(ws + 29884416);
    unsigned short* attb  = (unsigned short*)(ws + 36175872);

    // one fused cvt launch: x (3.15M), W_qkv (1.77M), W_out (0.59M)
    cvt3_f32_bf16<<<5376, 256, 0, stream>>>(
        x, TSEQ * CDIM, xb,
        W_qkv, QKVW * CDIM, wqkvb,
        W_out, CDIM * CDIM, woutb);

    // qkv = x @ W_qkv^T ; Q columns (<768) pre-scaled by 0.125*log2e.
    // V column-blocks (n0 >= 1536) write TRANSPOSED to vtb directly
    // (fused transpose_v). T=128 + XCD-chunked swizzle (576 blocks %8==0).
    gemm_nt_mfma<1, 1, 128><<<dim3(QKVW / 128, TSEQ / 128), 256, 0, stream>>>(
        xb, wqkvb, qkvb, TSEQ, QKVW, CDIM, CDIM, 0.125f * 1.44269504f, vtb);

    attn_mfma<<<dim3(NHEAD * (TSEQ / 64)), 256, 0, stream>>>(qkvb, vtb, attb);

    // out projection: T=64 tile (768 blocks) + XCD-chunked swizzle
    gemm_nt_mfma<0, 0, 64><<<dim3(CDIM / 64, TSEQ / 64), 256, 0, stream>>>(
        attb, woutb, out, TSEQ, CDIM, CDIM, 0, 1.0f, nullptr);
}